// Round 7
// baseline (127.520 us; speedup 1.0000x reference)
//
#include <hip/hip_runtime.h>
#include <math.h>

// Problem constants (fixed by setup_inputs): B=8, C=32, H=256, W=256, step=32.
#define BB 8
#define CC 32
#define HH 256
#define WW 256
#define HW_ (HH * WW)        // 65536
#define CHW_ (CC * HW_)      // 2097152

// One block per (b,h). 4 waves; wave wv handles channels {wv, wv+4, ..., wv+28}.
// Each thread owns 4 consecutive W positions -> every gather is an aligned
// contiguous float4 (shifts are mult-of-32; reflections reverse in-register),
// so all LDS traffic is ds_read_b128/ds_write_b128 and all global traffic is
// dwordx4. x rows are staged in WAVE-PRIVATE double-buffered LDS rows, gates
// in wave-private LDS -> zero __syncthreads() in the whole kernel.
__global__ __launch_bounds__(256, 4)
void symctrl2_kernel(const float* __restrict__ x,
                     const float* __restrict__ s,
                     const float* __restrict__ wg,
                     const float* __restrict__ w_param,
                     const float* __restrict__ b_param,
                     float* __restrict__ out) {
    const int bh = blockIdx.x;          // 0 .. B*H-1
    const int b  = bh >> 8;
    const int h  = bh & (HH - 1);
    const int wv = threadIdx.x >> 6;    // wave 0..3
    const int l  = threadIdx.x & 63;    // lane
    const int p0 = l << 2;              // first of my 4 positions

    __shared__ __align__(16) float x_lds[4][2][WW];  // [wave][dbuf][row]
    __shared__ float sg_lds[4][16];                  // [wave][gate]

    // --- gates: sigmoid(w_param*s[b,k]+b_param), wave-private, no barrier ---
    if (l < 11) {
        float v = w_param[0] * s[b * 11 + l] + b_param[0];
        sg_lds[wv][l] = 1.0f / (1.0f + expf(-v));
    }

    // --- per-thread source offsets (element offsets within the 256-row) ---
    int srcb[12];
    srcb[0] = p0;                                       // identity
    #pragma unroll
    for (int k = 1; k <= 7; ++k)                        // roll by 32k
        srcb[k] = (p0 - 32 * k) & (WW - 1);
    #pragma unroll
    for (int j = 0; j < 4; ++j)                         // flip about 32j+31
        srcb[8 + j] = (32 * j + 28 - p0) & (WW - 1);    // block start (c-p0-3)

    // --- gated weights, gathered from global w row (L1/L2 resident) ---
    // g[t] = 1 for t=0, sg[t-1] for t=1..11 (shift gates 0..6, flip gates 7..10)
    const float* wrow = wg + ((size_t)b * HH + h) * WW;
    float wr[12][4];
    float den0 = 0.f, den1 = 0.f, den2 = 0.f, den3 = 0.f;
    #pragma unroll
    for (int t = 0; t < 12; ++t) {
        const float4 w4 = *reinterpret_cast<const float4*>(wrow + srcb[t]);
        const float gt = (t == 0) ? 1.0f : sg_lds[wv][t - 1];
        if (t < 8) {            // position-ordered
            wr[t][0] = gt * w4.x; wr[t][1] = gt * w4.y;
            wr[t][2] = gt * w4.z; wr[t][3] = gt * w4.w;
        } else {                // reflection: reverse into position order
            wr[t][0] = gt * w4.w; wr[t][1] = gt * w4.z;
            wr[t][2] = gt * w4.y; wr[t][3] = gt * w4.x;
        }
        den0 += wr[t][0]; den1 += wr[t][1]; den2 += wr[t][2]; den3 += wr[t][3];
    }
    const float r0 = 1.0f / den0, r1 = 1.0f / den1,
                r2 = 1.0f / den2, r3 = 1.0f / den3;
    #pragma unroll
    for (int t = 0; t < 12; ++t) {      // fold 1/den into the weights
        wr[t][0] *= r0; wr[t][1] *= r1; wr[t][2] *= r2; wr[t][3] *= r3;
    }

    // --- channel sweep: 8 rows per wave, 1-deep prefetch, double-buffered LDS ---
    const float* xb = x   + (size_t)b * CHW_ + (size_t)h * WW + (size_t)wv * HW_;
    float*       ob = out + (size_t)b * CHW_ + (size_t)h * WW + (size_t)wv * HW_;

    float4 nxt = *reinterpret_cast<const float4*>(xb + p0);
    #pragma unroll
    for (int it = 0; it < 8; ++it) {
        float* row = x_lds[wv][it & 1];                 // compile-time after unroll
        *reinterpret_cast<float4*>(row + p0) = nxt;     // stage current row
        if (it < 7)                                     // prefetch next row
            nxt = *reinterpret_cast<const float4*>(
                xb + (size_t)(it + 1) * (4 * HW_) + p0);

        float a0 = 0.f, a1 = 0.f, a2 = 0.f, a3 = 0.f;
        #pragma unroll
        for (int t = 0; t < 12; ++t) {
            const float4 xq = *reinterpret_cast<const float4*>(row + srcb[t]);
            if (t < 8) {
                a0 = fmaf(wr[t][0], xq.x, a0);
                a1 = fmaf(wr[t][1], xq.y, a1);
                a2 = fmaf(wr[t][2], xq.z, a2);
                a3 = fmaf(wr[t][3], xq.w, a3);
            } else {            // reflection: x element reversed vs position
                a0 = fmaf(wr[t][0], xq.w, a0);
                a1 = fmaf(wr[t][1], xq.z, a1);
                a2 = fmaf(wr[t][2], xq.y, a2);
                a3 = fmaf(wr[t][3], xq.x, a3);
            }
        }
        float4 o4 = make_float4(a0, a1, a2, a3);
        *reinterpret_cast<float4*>(ob + (size_t)it * (4 * HW_) + p0) = o4;
    }
}

extern "C" void kernel_launch(void* const* d_in, const int* in_sizes, int n_in,
                              void* d_out, int out_size, void* d_ws, size_t ws_size,
                              hipStream_t stream) {
    const float* x  = (const float*)d_in[0];
    const float* s  = (const float*)d_in[1];
    const float* w  = (const float*)d_in[2];
    const float* wp = (const float*)d_in[3];
    const float* bp = (const float*)d_in[4];
    float* outp = (float*)d_out;

    dim3 grid(BB * HH);   // 2048 blocks, one per (b,h)
    dim3 block(256);      // 4 waves; each wave owns one channel-row at a time
    symctrl2_kernel<<<grid, block, 0, stream>>>(x, s, w, wp, bp, outp);
}

// Round 9
// 119.950 us; speedup vs baseline: 1.0631x; 1.0631x over previous
//
#include <hip/hip_runtime.h>
#include <math.h>

// Problem constants (fixed by setup_inputs): B=8, C=32, H=256, W=256, step=32.
#define BB 8
#define CC 32
#define HH 256
#define WW 256

// Block-coordinate decomposition: position i = 32*q + 4*u + e, q,u in [0,8), e in [0,4).
//   roll by 32k:          q -> (q-k)&7,  u,e unchanged          (in-register)
//   flip about 32j+31:    q -> (j-q)&7,  u -> 7-u, e -> 3-e     (DPP row_half_mirror)
// Lane layout: l = 8*row + u; wave = 8 channel-rows x 8 u-lanes. Lane (row,u)
// holds all 8 q-chunks (float4 each) of its channel-row -> shifts are register
// index moves, flips are one cross-lane u<->7-u swap = DPP row_half_mirror
// (VALU, no LDS pipe). Kernel uses ZERO LDS and ZERO barriers.
__device__ __forceinline__ float half_mirror(float v) {
    int i = __builtin_bit_cast(int, v);
    i = __builtin_amdgcn_update_dpp(i, i, 0x141, 0xf, 0xf, true); // row_half_mirror
    return __builtin_bit_cast(float, i);
}

__global__ __launch_bounds__(256, 2)
void symctrl2_kernel(const float* __restrict__ x,
                     const float* __restrict__ s,
                     const float* __restrict__ wg,
                     const float* __restrict__ w_param,
                     const float* __restrict__ b_param,
                     float* __restrict__ out) {
    const int bh  = blockIdx.x;             // one block per (b,h)
    const int b   = bh >> 8;
    const int h   = bh & (HH - 1);
    const int wv  = threadIdx.x >> 6;       // wave 0..3 -> channels 8wv..8wv+7
    const int l   = threadIdx.x & 63;
    const int row = l >> 3;                 // channel within the wave's group
    const int u   = l & 7;                  // float4-chunk within each 32-block
    const int c   = (wv << 3) + row;

    const float* wrow = wg  + ((size_t)b * HH + h) * WW;
    const float* xrow = x   + (((size_t)b * CC + c) * HH + h) * WW;
    float*       orow = out + (((size_t)b * CC + c) * HH + h) * WW;

    // ---- issue all loads up front; latency hides under gates+den compute ----
    float4 wq[8], xq[8];
    #pragma unroll
    for (int q = 0; q < 8; ++q)
        wq[q] = *reinterpret_cast<const float4*>(wrow + 32 * q + 4 * u);
    #pragma unroll
    for (int q = 0; q < 8; ++q)
        xq[q] = *reinterpret_cast<const float4*>(xrow + 32 * q + 4 * u);

    // ---- gates: sigmoid(w_param*s[b,k]+b_param); uniform, every lane computes ----
    const float wp = w_param[0], bpv = b_param[0];
    float gk[8], gf[4];
    gk[0] = 1.0f;                           // identity term
    #pragma unroll
    for (int k = 0; k < 7; ++k) {           // shift gates
        float v = wp * s[b * 11 + k] + bpv;
        gk[k + 1] = 1.0f / (1.0f + __expf(-v));
    }
    #pragma unroll
    for (int j = 0; j < 4; ++j) {           // flip gates
        float v = wp * s[b * 11 + 7 + j] + bpv;
        gf[j] = 1.0f / (1.0f + __expf(-v));
    }

    // ---- denominator (channel-independent; identical across row-groups) ----
    float den[8][4];
    #pragma unroll
    for (int g = 0; g < 8; ++g) {           // shift part: circular correlation in q
        float d0 = 0.f, d1 = 0.f, d2 = 0.f, d3 = 0.f;
        #pragma unroll
        for (int k = 0; k < 8; ++k) {
            const float4 w4 = wq[(g - k) & 7];
            d0 = fmaf(gk[k], w4.x, d0);
            d1 = fmaf(gk[k], w4.y, d1);
            d2 = fmaf(gk[k], w4.z, d2);
            d3 = fmaf(gk[k], w4.w, d3);
        }
        den[g][0] = d0; den[g][1] = d1; den[g][2] = d2; den[g][3] = d3;
    }
    #pragma unroll
    for (int q = 0; q < 8; ++q) {           // flip part via DPP mirror of w
        const float m0 = half_mirror(wq[q].x);
        const float m1 = half_mirror(wq[q].y);
        const float m2 = half_mirror(wq[q].z);
        const float m3 = half_mirror(wq[q].w);
        #pragma unroll
        for (int j = 0; j < 4; ++j) {
            const int g = (j - q) & 7;
            den[g][0] = fmaf(gf[j], m3, den[g][0]);   // e=0 uses elem 3
            den[g][1] = fmaf(gf[j], m2, den[g][1]);
            den[g][2] = fmaf(gf[j], m1, den[g][2]);
            den[g][3] = fmaf(gf[j], m0, den[g][3]);
        }
    }
    float rden[8][4];
    #pragma unroll
    for (int g = 0; g < 8; ++g)
        #pragma unroll
        for (int e = 0; e < 4; ++e)
            rden[g][e] = __builtin_amdgcn_rcpf(den[g][e]);

    // ---- products P = w*x (w,x die here), numerator, scale, store ----
    float P[8][4];
    #pragma unroll
    for (int q = 0; q < 8; ++q) {
        P[q][0] = wq[q].x * xq[q].x;
        P[q][1] = wq[q].y * xq[q].y;
        P[q][2] = wq[q].z * xq[q].z;
        P[q][3] = wq[q].w * xq[q].w;
    }
    float num[8][4];
    #pragma unroll
    for (int g = 0; g < 8; ++g) {           // shift part
        float n0 = 0.f, n1 = 0.f, n2 = 0.f, n3 = 0.f;
        #pragma unroll
        for (int k = 0; k < 8; ++k) {
            const int q = (g - k) & 7;
            n0 = fmaf(gk[k], P[q][0], n0);
            n1 = fmaf(gk[k], P[q][1], n1);
            n2 = fmaf(gk[k], P[q][2], n2);
            n3 = fmaf(gk[k], P[q][3], n3);
        }
        num[g][0] = n0; num[g][1] = n1; num[g][2] = n2; num[g][3] = n3;
    }
    #pragma unroll
    for (int q = 0; q < 8; ++q) {           // flip part via DPP mirror of P
        const float m0 = half_mirror(P[q][0]);
        const float m1 = half_mirror(P[q][1]);
        const float m2 = half_mirror(P[q][2]);
        const float m3 = half_mirror(P[q][3]);
        #pragma unroll
        for (int j = 0; j < 4; ++j) {
            const int g = (j - q) & 7;
            num[g][0] = fmaf(gf[j], m3, num[g][0]);
            num[g][1] = fmaf(gf[j], m2, num[g][1]);
            num[g][2] = fmaf(gf[j], m1, num[g][2]);
            num[g][3] = fmaf(gf[j], m0, num[g][3]);
        }
    }
    #pragma unroll
    for (int g = 0; g < 8; ++g) {
        float4 o;
        o.x = num[g][0] * rden[g][0];
        o.y = num[g][1] * rden[g][1];
        o.z = num[g][2] * rden[g][2];
        o.w = num[g][3] * rden[g][3];
        *reinterpret_cast<float4*>(orow + 32 * g + 4 * u) = o;
    }
}

extern "C" void kernel_launch(void* const* d_in, const int* in_sizes, int n_in,
                              void* d_out, int out_size, void* d_ws, size_t ws_size,
                              hipStream_t stream) {
    const float* x  = (const float*)d_in[0];
    const float* s  = (const float*)d_in[1];
    const float* w  = (const float*)d_in[2];
    const float* wp = (const float*)d_in[3];
    const float* bp = (const float*)d_in[4];
    float* outp = (float*)d_out;

    dim3 grid(BB * HH);   // 2048 blocks, one per (b,h)
    dim3 block(256);      // 4 waves x 8 channels each = all 32 channels
    symctrl2_kernel<<<grid, block, 0, stream>>>(x, s, w, wp, bp, outp);
}